// Round 15
// baseline (209.034 us; speedup 1.0000x reference)
//
#include <hip/hip_runtime.h>
#include <hip/hip_bf16.h>

#define BQ 8      // batches
#define NN 2048   // train rows (keys)
#define MM 1024   // test rows (queries)
#define EE 512    // input size
#define NH 6      // heads
#define AA 384    // attn size (NH*64)
#define CC 512    // classes

#define KROW_B (AA * 2)          // 768 bytes per K row
#define TILE_B (16 * KROW_B)     // 12288 bytes per 16-row K tile
#define STILE_B (32 * KROW_B)    // 24576 bytes per 32-row super-tile
#define WROW_B (EE * 2)          // 1024 bytes per W row
#define WTILE_B (16 * WROW_B)    // 16384 bytes per 16-row W tile

// fold SDPA scale and log2(e) into Q so the score pass uses raw v_exp_f32 (exp2)
#define QSCALE 0.1803368801111204f   // 0.125 * log2(e)

typedef __bf16 bf16x8 __attribute__((ext_vector_type(8)));
typedef float  f32x4  __attribute__((ext_vector_type(4)));
typedef float  f32x2  __attribute__((ext_vector_type(2)));
using bf16 = __hip_bfloat16;

static __device__ __forceinline__ f32x4 mfma16(bf16x8 a, bf16x8 b, f32x4 c) {
  return __builtin_amdgcn_mfma_f32_16x16x32_bf16(a, b, c, 0, 0, 0);
}

typedef __attribute__((address_space(1))) const void gconst_void;
typedef __attribute__((address_space(3))) void lds_void_t;
static __device__ __forceinline__ void ld_lds16(const void* g, void* l) {
  __builtin_amdgcn_global_load_lds((gconst_void*)g, (lds_void_t*)l, 16, 0, 0);
}

// ---------- fp8 e4m3 pack/unpack (HW builtins on gfx950; consistent SW fallback) ----------
static __device__ __forceinline__ unsigned enc_fp8(float f) {
  unsigned b = __float_as_uint(f) + 0x00080000u;       // round at mantissa bit 19
  int e = (int)((b >> 23) & 0xFF) - 120;               // e4m3 biased exponent
  if (e <= 0) return 0u;
  if (e >= 16) return 0x7Eu;                           // clamp to 448
  return ((unsigned)e << 3) | ((b >> 20) & 7u);
}
static __device__ __forceinline__ float dec_fp8(unsigned u) {
  unsigned e = (u >> 3) & 0xFu;
  if (e == 0) return 0.f;
  return __uint_as_float(((e + 120u) << 23) | ((u & 7u) << 20));
}
static __device__ __forceinline__ unsigned pk4(float a, float b, float c, float d) {
#if __has_builtin(__builtin_amdgcn_cvt_pk_fp8_f32)
  int v = __builtin_amdgcn_cvt_pk_fp8_f32(a, b, 0, false);
  v = __builtin_amdgcn_cvt_pk_fp8_f32(c, d, v, true);
  return (unsigned)v;
#else
  return enc_fp8(a) | (enc_fp8(b) << 8) | (enc_fp8(c) << 16) | (enc_fp8(d) << 24);
#endif
}
static __device__ __forceinline__ unsigned pk2(float a, float b) {
#if __has_builtin(__builtin_amdgcn_cvt_pk_fp8_f32)
  return (unsigned)__builtin_amdgcn_cvt_pk_fp8_f32(a, b, 0, false);
#else
  return enc_fp8(a) | (enc_fp8(b) << 8);
#endif
}
template <bool HI>
static __device__ __forceinline__ f32x2 upk2(unsigned d) {
#if __has_builtin(__builtin_amdgcn_cvt_pk_f32_fp8)
  return __builtin_amdgcn_cvt_pk_f32_fp8((int)d, HI);
#else
  f32x2 r;
  r[0] = dec_fp8((d >> (HI ? 16 : 0)) & 0xFFu);
  r[1] = dec_fp8((d >> (HI ? 24 : 8)) & 0xFFu);
  return r;
#endif
}

// ---------------- prep: W transposes (blocks 0..95) + CSR build (96..103) ----------------
// offs[b][c] = start of class c's run in sorted order; idxs[b][p] = original n at sorted pos p
__global__ __launch_bounds__(512) void prep_kernel(
    const float* __restrict__ Wq, const float* __restrict__ Wk,
    bf16* __restrict__ WqT, bf16* __restrict__ WkT,
    const int* __restrict__ targets, int* __restrict__ offs, int* __restrict__ idxs)
{
  __shared__ float t[64][65];
  __shared__ int cnt[CC], ssum[CC], pos[CC];
  int bid = blockIdx.x, tid = threadIdx.x;
  if (bid < 96) {
    if (tid >= 256) { __syncthreads(); __syncthreads(); return; }
    int id = bid;
    const float* W = (id < 48) ? Wq : Wk;
    bf16* WT = (id < 48) ? WqT : WkT;
    if (id >= 48) id -= 48;
    int kb = (id / 6) * 64, nb = (id % 6) * 64;
    int lr = tid >> 4, lc = (tid & 15) * 4;
    #pragma unroll
    for (int p = 0; p < 4; p++) {
      int k = lr + p * 16;
      float4 v = *reinterpret_cast<const float4*>(W + (size_t)(kb + k) * AA + nb + lc);
      t[k][lc] = v.x; t[k][lc + 1] = v.y; t[k][lc + 2] = v.z; t[k][lc + 3] = v.w;
    }
    __syncthreads();
    #pragma unroll
    for (int p = 0; p < 4; p++) {
      int n = lr + p * 16;
      bf16* dst = WT + (size_t)(nb + n) * EE + kb + lc;
      dst[0] = __float2bfloat16(t[lc][n]);
      dst[1] = __float2bfloat16(t[lc + 1][n]);
      dst[2] = __float2bfloat16(t[lc + 2][n]);
      dst[3] = __float2bfloat16(t[lc + 3][n]);
    }
    __syncthreads();
    return;
  }
  // ---- CSR build ----
  int b = bid - 96;
  cnt[tid] = 0;
  __syncthreads();
  int tv[4];
  #pragma unroll
  for (int i = 0; i < 4; i++) {
    tv[i] = targets[b * NN + tid * 4 + i];
    atomicAdd(&cnt[tv[i]], 1);
  }
  __syncthreads();
  ssum[tid] = cnt[tid];
  __syncthreads();
  for (int d = 1; d < CC; d <<= 1) {
    int v = (tid >= d) ? ssum[tid - d] : 0;
    __syncthreads();
    ssum[tid] += v;
    __syncthreads();
  }
  int excl = ssum[tid] - cnt[tid];
  offs[b * (CC + 1) + tid] = excl;
  if (tid == CC - 1) offs[b * (CC + 1) + CC] = NN;
  pos[tid] = excl;
  __syncthreads();
  #pragma unroll
  for (int i = 0; i < 4; i++) {
    int p = atomicAdd(&pos[tv[i]], 1);
    idxs[b * NN + p] = tid * 4 + i;
  }
}

// ---------------- projections (f32 in, bf16 out); K rows written CLASS-SORTED ----------------
__global__ __launch_bounds__(256, 3) void proj_kernel(
    const float* __restrict__ test, const float* __restrict__ train,
    const bf16* __restrict__ WqT, const bf16* __restrict__ WkT,
    const float* __restrict__ bq, const float* __restrict__ bk,
    const int* __restrict__ idxs,
    bf16* __restrict__ Qb, bf16* __restrict__ Kb)
{
  __shared__ char wbuf[3][WTILE_B];   // 48 KB
  int tid = threadIdx.x, wid = tid >> 6, lane = tid & 63;
  int bid = blockIdx.x;
  int sub = bid & 1, unit = bid >> 1;
  const bf16* WT; const float* bias; bf16* C; float scale; int m0;
  const float* arow;
  int row = lane & 15, hi = lane >> 4;
  if (unit < 128) {
    WT = WqT; bias = bq; C = Qb; scale = QSCALE; m0 = unit * 64 + wid * 16;
    arow = test + (size_t)(m0 + row) * EE + hi * 8;
  } else {
    WT = WkT; bias = bk; C = Kb; scale = 1.0f;
    int g0 = (unit - 128) * 64 + wid * 16;        // global sorted row base
    m0 = g0;
    int g = g0 + row;
    int b = g >> 11, pos = g & (NN - 1);
    int srcrow = idxs[b * NN + pos];              // original train row
    arow = train + ((size_t)b * NN + srcrow) * EE + hi * 8;
  }

  bf16x8 af[16];
  #pragma unroll
  for (int ks = 0; ks < 16; ks++) {
    float4 u = *reinterpret_cast<const float4*>(arow + ks * 32);
    float4 v = *reinterpret_cast<const float4*>(arow + ks * 32 + 4);
    bf16x8 f;
    f[0] = (__bf16)u.x; f[1] = (__bf16)u.y; f[2] = (__bf16)u.z; f[3] = (__bf16)u.w;
    f[4] = (__bf16)v.x; f[5] = (__bf16)v.y; f[6] = (__bf16)v.z; f[7] = (__bf16)v.w;
    af[ks] = f;
  }

  int ldso[4], srco[4];
  #pragma unroll
  for (int i = 0; i < 4; i++) {
    int off = tid * 16 + i * 4096;
    int rw = off >> 10, c = off & 1023;
    ldso[i] = off;
    srco[i] = rw * WROW_B + (c ^ ((rw & 7) << 4));
  }
  const char* wgbase = (const char*)WT + (size_t)sub * 12 * WTILE_B;
  int sw = (row & 7) << 4;

  auto stage = [&](int t, int buf) {
    const char* src = wgbase + (size_t)t * WTILE_B;
    #pragma unroll
    for (int i = 0; i < 4; i++) ld_lds16(src + srco[i], wbuf[buf] + ldso[i]);
  };
  auto compute = [&](int buf, int t) {
    const char* wb = wbuf[buf] + row * WROW_B;
    f32x4 acc0 = {0.f, 0.f, 0.f, 0.f}, acc1 = {0.f, 0.f, 0.f, 0.f};
    #pragma unroll
    for (int ks = 0; ks < 16; ks += 2) {
      bf16x8 w0 = *reinterpret_cast<const bf16x8*>(wb + ((hi * 16 + ks * 64) ^ sw));
      bf16x8 w1 = *reinterpret_cast<const bf16x8*>(wb + ((hi * 16 + (ks + 1) * 64) ^ sw));
      acc0 = mfma16(af[ks], w0, acc0);
      acc1 = mfma16(af[ks + 1], w1, acc1);
    }
    f32x4 acc = acc0 + acc1;
    int ocol = (sub * 12 + t) * 16 + row;
    float bv = bias[ocol];
    #pragma unroll
    for (int j = 0; j < 4; j++)
      C[(size_t)(m0 + hi * 4 + j) * AA + ocol] = __float2bfloat16((acc[j] + bv) * scale);
  };

  stage(0, 0);
  stage(1, 1);
  asm volatile("s_waitcnt vmcnt(4)" ::: "memory");
  __builtin_amdgcn_s_barrier();
  __builtin_amdgcn_sched_barrier(0);
  stage(2, 2);
  compute(0, 0);

  int cur = 1, stg = 0;
  #pragma unroll 1
  for (int t = 1; t < 11; t++) {
    asm volatile("s_waitcnt vmcnt(8)" ::: "memory");
    __builtin_amdgcn_s_barrier();
    __builtin_amdgcn_sched_barrier(0);
    if (t < 10) stage(t + 2, stg);
    compute(cur, t);
    cur = cur + 1 < 3 ? cur + 1 : 0;
    stg = stg + 1 < 3 ? stg + 1 : 0;
  }
  asm volatile("s_waitcnt vmcnt(4)" ::: "memory");
  __builtin_amdgcn_s_barrier();
  __builtin_amdgcn_sched_barrier(0);
  compute(cur, 11);
}

// ---------------- score pass: per-head unnormalized exp2 weights -> fp8x6 packed 8B ----------------
// n-axis is class-sorted (inherits Kb order). grid = 512, 256 thr, 32 m-rows/wave
__global__ __launch_bounds__(256, 2) void spass_kernel(
    const bf16* __restrict__ Qb, const bf16* __restrict__ Kb, char* __restrict__ Wh)
{
  __shared__ char kbuf[2][STILE_B];    // 48 KB
  int id = blockIdx.x;
  int b = id & 7, r = id >> 3, mt = r & 7, nc = r >> 3;
  int tid = threadIdx.x, wid = tid >> 6, lane = tid & 63;
  int m0 = mt * 128 + wid * 32, n0 = nc * 256;
  int row = lane & 15, hi = lane >> 4;

  bf16x8 qf[2][12];
  #pragma unroll
  for (int s = 0; s < 2; s++) {
    const bf16* qrow = Qb + ((size_t)(b * MM + m0 + s * 16 + row)) * AA + hi * 8;
    #pragma unroll
    for (int ks = 0; ks < 12; ks++) qf[s][ks] = *reinterpret_cast<const bf16x8*>(qrow + ks * 32);
  }

  int ldso[6], srco[6];
  #pragma unroll
  for (int i = 0; i < 6; i++) {
    int off = tid * 16 + i * 4096;
    int rw = off / KROW_B, c = off - rw * KROW_B;
    ldso[i] = off;
    srco[i] = rw * KROW_B + (c ^ ((rw & 7) << 4));
  }
  const char* kgbase = (const char*)(Kb + ((size_t)(b * NN + n0)) * AA);

  int sw = (row & 7) << 4;
  int rbase = row * KROW_B;
  int x0 = rbase + ((hi * 16) ^ sw);
  int x1 = rbase + (((hi * 16) + 64) ^ sw);

  auto stage = [&](int t, int buf) {
    const char* src = kgbase + (size_t)t * STILE_B;
    #pragma unroll
    for (int i = 0; i < 6; i++) ld_lds16(src + srco[i], kbuf[buf] + ldso[i]);
  };
  auto compute = [&](int buf, int st) {          // issues 16 x 8B stores
    #pragma unroll
    for (int sub = 0; sub < 2; sub++) {
      const char* kb = kbuf[buf] + sub * TILE_B;
      float w[2][NH][4];
      __builtin_amdgcn_s_setprio(1);
      #pragma unroll
      for (int h = 0; h < NH; h++) {
        bf16x8 k0 = *reinterpret_cast<const bf16x8*>(kb + h * 128 + x0);
        bf16x8 k1 = *reinterpret_cast<const bf16x8*>(kb + h * 128 + x1);
        f32x4 a0 = {0.f, 0.f, 0.f, 0.f}, a1 = {0.f, 0.f, 0.f, 0.f};
        a0 = mfma16(qf[0][2 * h], k0, a0);
        a1 = mfma16(qf[1][2 * h], k0, a1);
        a0 = mfma16(qf[0][2 * h + 1], k1, a0);
        a1 = mfma16(qf[1][2 * h + 1], k1, a1);
        #pragma unroll
        for (int j = 0; j < 4; j++) {
          w[0][h][j] = __builtin_amdgcn_exp2f(a0[j]);
          w[1][h][j] = __builtin_amdgcn_exp2f(a1[j]);
        }
      }
      __builtin_amdgcn_s_setprio(0);
      int n = n0 + (st * 2 + sub) * 16 + row;
      #pragma unroll
      for (int s = 0; s < 2; s++)
        #pragma unroll
        for (int j = 0; j < 4; j++) {
          unsigned d0 = pk4(w[s][0][j], w[s][1][j], w[s][2][j], w[s][3][j]);
          unsigned d1 = pk2(w[s][4][j], w[s][5][j]);
          int m = m0 + s * 16 + hi * 4 + j;
          *reinterpret_cast<uint2*>(Wh + (((size_t)(b * MM + m)) * NN + n) * 8) = make_uint2(d0, d1);
        }
    }
  };

  stage(0, 0);
  asm volatile("s_waitcnt vmcnt(0)" ::: "memory");   // drain Q frags + tile 0
  __builtin_amdgcn_s_barrier();
  __builtin_amdgcn_sched_barrier(0);
  stage(1, 1);
  compute(0, 0);

  #pragma unroll 1
  for (int i = 1; i < 8; i++) {
    // queue: [L(i):6, S(i-1):16] -> vmcnt(16) retires exactly L(i)
    asm volatile("s_waitcnt vmcnt(16)" ::: "memory");
    __builtin_amdgcn_s_barrier();
    __builtin_amdgcn_sched_barrier(0);
    if (i < 7) stage(i + 1, (i + 1) & 1);
    compute(i & 1, i);
  }
}

// ---------------- gather: contiguous per-class runs, coalesced global streaming ----------------
// grid = 8b x 128 mt(8m) = 1024, 512 thr (thread = class)
__global__ __launch_bounds__(512) void gather_kernel(
    const char* __restrict__ Wh, const int* __restrict__ offs, float* __restrict__ out)
{
  __shared__ float wred[8][48];
  __shared__ float rzs[48];
  int id = blockIdx.x;
  int b = id & 7, mt = id >> 3;
  int m0 = mt * 8;
  int tid = threadIdx.x, wid = tid >> 6, lane = tid & 63;
  int c = tid;

  int o0 = offs[b * (CC + 1) + c];
  int o1 = offs[b * (CC + 1) + c + 1];
  const char* rbase = Wh + ((size_t)(b * MM + m0)) * (NN * 8);

  float B[8][NH];
  #pragma unroll
  for (int m = 0; m < 8; m++)
    #pragma unroll
    for (int h = 0; h < NH; h++) B[m][h] = 0.f;

  #pragma unroll 1
  for (int i = o0; i < o1; i++) {
    uint2 u[8];
    #pragma unroll
    for (int m = 0; m < 8; m++)
      u[m] = *reinterpret_cast<const uint2*>(rbase + (size_t)m * (NN * 8) + (size_t)i * 8);
    #pragma unroll
    for (int m = 0; m < 8; m++) {
      f32x2 p0 = upk2<false>(u[m].x);
      f32x2 p1 = upk2<true>(u[m].x);
      f32x2 p2 = upk2<false>(u[m].y);
      B[m][0] += p0[0]; B[m][1] += p0[1];
      B[m][2] += p1[0]; B[m][3] += p1[1];
      B[m][4] += p2[0]; B[m][5] += p2[1];
    }
  }

  // block reduce over all 512 classes -> Z[m][h]
  #pragma unroll
  for (int m = 0; m < 8; m++)
    #pragma unroll
    for (int h = 0; h < NH; h++) {
      float t = B[m][h];
      t += __shfl_xor(t, 1);  t += __shfl_xor(t, 2);  t += __shfl_xor(t, 4);
      t += __shfl_xor(t, 8);  t += __shfl_xor(t, 16); t += __shfl_xor(t, 32);
      if (lane == 0) wred[wid][m * NH + h] = t;
    }
  __syncthreads();
  if (tid < 48) {
    float z = 0.f;
    #pragma unroll
    for (int w = 0; w < 8; w++) z += wred[w][tid];
    rzs[tid] = 1.0f / (6.0f * z);
  }
  __syncthreads();

  #pragma unroll
  for (int m = 0; m < 8; m++) {
    float v = 0.f;
    #pragma unroll
    for (int h = 0; h < NH; h++) v += B[m][h] * rzs[m * NH + h];
    out[((size_t)(m0 + m) * BQ + b) * CC + c] = __logf(fmaxf(v, 1e-5f) + 3e-5f);
  }
}

extern "C" void kernel_launch(void* const* d_in, const int* in_sizes, int n_in,
                              void* d_out, int out_size, void* d_ws, size_t ws_size,
                              hipStream_t stream) {
  const float* train = (const float*)d_in[0];
  const float* test  = (const float*)d_in[1];
  const int*   tgt   = (const int*)d_in[2];
  const float* Wq    = (const float*)d_in[3];
  const float* bq    = (const float*)d_in[4];
  const float* Wk    = (const float*)d_in[5];
  const float* bk    = (const float*)d_in[6];
  float* out = (float*)d_out;

  char* ws = (char*)d_ws;
  bf16*  WqT  = (bf16*)(ws);                       //     393,216 B
  bf16*  WkT  = (bf16*)(ws + 393216);              //     393,216 B
  bf16*  Qb   = (bf16*)(ws + 786432);              //   6,291,456 B
  bf16*  Kb   = (bf16*)(ws + 7077888);             //  12,582,912 B
  char*  Wh   = (char*)(ws + 19660800);            // 134,217,728 B (fp8x6+pad, class-sorted n)
  int*   offs = (int*)(ws + 153878528);            //      16,416 B
  int*   idxs = (int*)(ws + 153894944);            //      65,536 B

  prep_kernel<<<104, 512, 0, stream>>>(Wq, Wk, WqT, WkT, tgt, offs, idxs);
  proj_kernel<<<768, 256, 0, stream>>>(test, train, WqT, WkT, bq, bk, idxs, Qb, Kb);
  spass_kernel<<<512, 256, 0, stream>>>(Qb, Kb, Wh);
  gather_kernel<<<1024, 512, 0, stream>>>(Wh, offs, out);
}

// Round 16
// 103.658 us; speedup vs baseline: 2.0166x; 2.0166x over previous
//
#include <hip/hip_runtime.h>
#include <hip/hip_bf16.h>

#define BQ 8      // batches
#define NN 2048   // train rows (keys)
#define MM 1024   // test rows (queries)
#define EE 512    // input size
#define NH 6      // heads
#define AA 384    // attn size (NH*64)
#define CC 512    // classes

#define KROW_B (AA * 2)          // 768 bytes per K row
#define TILE_B (16 * KROW_B)     // 12288 bytes per 16-row K tile
#define STILE_B (32 * KROW_B)    // 24576 bytes per 32-row super-tile
#define WROW_B (EE * 2)          // 1024 bytes per W row
#define WTILE_B (16 * WROW_B)    // 16384 bytes per 16-row W tile

// fold SDPA scale and log2(e) into Q so score passes use raw v_exp_f32 (exp2)
#define QSCALE 0.1803368801111204f   // 0.125 * log2(e)

typedef __bf16 bf16x8 __attribute__((ext_vector_type(8)));
typedef float  f32x4  __attribute__((ext_vector_type(4)));
using bf16 = __hip_bfloat16;

static __device__ __forceinline__ f32x4 mfma16(bf16x8 a, bf16x8 b, f32x4 c) {
  return __builtin_amdgcn_mfma_f32_16x16x32_bf16(a, b, c, 0, 0, 0);
}

typedef __attribute__((address_space(1))) const void gconst_void;
typedef __attribute__((address_space(3))) void lds_void_t;
static __device__ __forceinline__ void ld_lds16(const void* g, void* l) {
  __builtin_amdgcn_global_load_lds((gconst_void*)g, (lds_void_t*)l, 16, 0, 0);
}

static __device__ __forceinline__ unsigned short f2bfu(float x) {
  union { __hip_bfloat16 h; unsigned short u; } v;
  v.h = __float2bfloat16(x);
  return v.u;
}
static __device__ __forceinline__ float bf2f(unsigned short u) {
  union { unsigned int i; float f; } x;
  x.i = ((unsigned int)u) << 16;
  return x.f;
}

// ---------------- prep: W transposes (blocks 0..95) + CSR build (96..103) ----------------
// offs[b][c] = start of class c's run in sorted order; idxs[b][p] = original n at sorted pos p
__global__ __launch_bounds__(512) void prep_kernel(
    const float* __restrict__ Wq, const float* __restrict__ Wk,
    bf16* __restrict__ WqT, bf16* __restrict__ WkT,
    const int* __restrict__ targets, int* __restrict__ offs, int* __restrict__ idxs)
{
  __shared__ float t[64][65];
  __shared__ int cnt[CC], ssum[CC], pos[CC];
  int bid = blockIdx.x, tid = threadIdx.x;
  if (bid < 96) {
    if (tid >= 256) { __syncthreads(); __syncthreads(); return; }
    int id = bid;
    const float* W = (id < 48) ? Wq : Wk;
    bf16* WT = (id < 48) ? WqT : WkT;
    if (id >= 48) id -= 48;
    int kb = (id / 6) * 64, nb = (id % 6) * 64;
    int lr = tid >> 4, lc = (tid & 15) * 4;
    #pragma unroll
    for (int p = 0; p < 4; p++) {
      int k = lr + p * 16;
      float4 v = *reinterpret_cast<const float4*>(W + (size_t)(kb + k) * AA + nb + lc);
      t[k][lc] = v.x; t[k][lc + 1] = v.y; t[k][lc + 2] = v.z; t[k][lc + 3] = v.w;
    }
    __syncthreads();
    #pragma unroll
    for (int p = 0; p < 4; p++) {
      int n = lr + p * 16;
      bf16* dst = WT + (size_t)(nb + n) * EE + kb + lc;
      dst[0] = __float2bfloat16(t[lc][n]);
      dst[1] = __float2bfloat16(t[lc + 1][n]);
      dst[2] = __float2bfloat16(t[lc + 2][n]);
      dst[3] = __float2bfloat16(t[lc + 3][n]);
    }
    __syncthreads();
    return;
  }
  // ---- CSR build ----
  int b = bid - 96;
  cnt[tid] = 0;
  __syncthreads();
  int tv[4];
  #pragma unroll
  for (int i = 0; i < 4; i++) {
    tv[i] = targets[b * NN + tid * 4 + i];
    atomicAdd(&cnt[tv[i]], 1);
  }
  __syncthreads();
  ssum[tid] = cnt[tid];
  __syncthreads();
  for (int d = 1; d < CC; d <<= 1) {
    int v = (tid >= d) ? ssum[tid - d] : 0;
    __syncthreads();
    ssum[tid] += v;
    __syncthreads();
  }
  int excl = ssum[tid] - cnt[tid];
  offs[b * (CC + 1) + tid] = excl;
  if (tid == CC - 1) offs[b * (CC + 1) + CC] = NN;
  pos[tid] = excl;
  __syncthreads();
  #pragma unroll
  for (int i = 0; i < 4; i++) {
    int p = atomicAdd(&pos[tv[i]], 1);
    idxs[b * NN + p] = tid * 4 + i;
  }
}

// ---------------- projections (f32 in, bf16 out); K rows written CLASS-SORTED ----------------
__global__ __launch_bounds__(256, 3) void proj_kernel(
    const float* __restrict__ test, const float* __restrict__ train,
    const bf16* __restrict__ WqT, const bf16* __restrict__ WkT,
    const float* __restrict__ bq, const float* __restrict__ bk,
    const int* __restrict__ idxs,
    bf16* __restrict__ Qb, bf16* __restrict__ Kb)
{
  __shared__ char wbuf[3][WTILE_B];   // 48 KB
  int tid = threadIdx.x, wid = tid >> 6, lane = tid & 63;
  int bid = blockIdx.x;
  int sub = bid & 1, unit = bid >> 1;
  const bf16* WT; const float* bias; bf16* C; float scale; int m0;
  const float* arow;
  int row = lane & 15, hi = lane >> 4;
  if (unit < 128) {
    WT = WqT; bias = bq; C = Qb; scale = QSCALE; m0 = unit * 64 + wid * 16;
    arow = test + (size_t)(m0 + row) * EE + hi * 8;
  } else {
    WT = WkT; bias = bk; C = Kb; scale = 1.0f;
    int g0 = (unit - 128) * 64 + wid * 16;        // global sorted row base
    m0 = g0;
    int g = g0 + row;
    int b = g >> 11, pos = g & (NN - 1);
    int srcrow = idxs[b * NN + pos];              // original train row
    arow = train + ((size_t)b * NN + srcrow) * EE + hi * 8;
  }

  bf16x8 af[16];
  #pragma unroll
  for (int ks = 0; ks < 16; ks++) {
    float4 u = *reinterpret_cast<const float4*>(arow + ks * 32);
    float4 v = *reinterpret_cast<const float4*>(arow + ks * 32 + 4);
    bf16x8 f;
    f[0] = (__bf16)u.x; f[1] = (__bf16)u.y; f[2] = (__bf16)u.z; f[3] = (__bf16)u.w;
    f[4] = (__bf16)v.x; f[5] = (__bf16)v.y; f[6] = (__bf16)v.z; f[7] = (__bf16)v.w;
    af[ks] = f;
  }

  int ldso[4], srco[4];
  #pragma unroll
  for (int i = 0; i < 4; i++) {
    int off = tid * 16 + i * 4096;
    int rw = off >> 10, c = off & 1023;
    ldso[i] = off;
    srco[i] = rw * WROW_B + (c ^ ((rw & 7) << 4));
  }
  const char* wgbase = (const char*)WT + (size_t)sub * 12 * WTILE_B;
  int sw = (row & 7) << 4;

  auto stage = [&](int t, int buf) {
    const char* src = wgbase + (size_t)t * WTILE_B;
    #pragma unroll
    for (int i = 0; i < 4; i++) ld_lds16(src + srco[i], wbuf[buf] + ldso[i]);
  };
  auto compute = [&](int buf, int t) {
    const char* wb = wbuf[buf] + row * WROW_B;
    f32x4 acc0 = {0.f, 0.f, 0.f, 0.f}, acc1 = {0.f, 0.f, 0.f, 0.f};
    #pragma unroll
    for (int ks = 0; ks < 16; ks += 2) {
      bf16x8 w0 = *reinterpret_cast<const bf16x8*>(wb + ((hi * 16 + ks * 64) ^ sw));
      bf16x8 w1 = *reinterpret_cast<const bf16x8*>(wb + ((hi * 16 + (ks + 1) * 64) ^ sw));
      acc0 = mfma16(af[ks], w0, acc0);
      acc1 = mfma16(af[ks + 1], w1, acc1);
    }
    f32x4 acc = acc0 + acc1;
    int ocol = (sub * 12 + t) * 16 + row;
    float bv = bias[ocol];
    #pragma unroll
    for (int j = 0; j < 4; j++)
      C[(size_t)(m0 + hi * 4 + j) * AA + ocol] = __float2bfloat16((acc[j] + bv) * scale);
  };

  stage(0, 0);
  stage(1, 1);
  asm volatile("s_waitcnt vmcnt(4)" ::: "memory");
  __builtin_amdgcn_s_barrier();
  __builtin_amdgcn_sched_barrier(0);
  stage(2, 2);
  compute(0, 0);

  int cur = 1, stg = 0;
  #pragma unroll 1
  for (int t = 1; t < 11; t++) {
    asm volatile("s_waitcnt vmcnt(8)" ::: "memory");
    __builtin_amdgcn_s_barrier();
    __builtin_amdgcn_sched_barrier(0);
    if (t < 10) stage(t + 2, stg);
    compute(cur, t);
    cur = cur + 1 < 3 ? cur + 1 : 0;
    stg = stg + 1 < 3 ? stg + 1 : 0;
  }
  asm volatile("s_waitcnt vmcnt(4)" ::: "memory");
  __builtin_amdgcn_s_barrier();
  __builtin_amdgcn_sched_barrier(0);
  compute(cur, 11);
}

// ---------------- pass 1: Z partials. 32 m-rows/wave, supertile 2-buf pipeline ----------------
// grid = 8b x 8mt(128m) x 8nc(256n) = 512
__global__ __launch_bounds__(256, 2) void zpass_kernel(
    const bf16* __restrict__ Qb, const bf16* __restrict__ Kb, float* __restrict__ Zp)
{
  __shared__ char kbuf[2][STILE_B];    // 48 KB
  int id = blockIdx.x;
  int b = id & 7, r = id >> 3, mt = r & 7, nc = r >> 3;
  int tid = threadIdx.x, wid = tid >> 6, lane = tid & 63;
  int m0 = mt * 128 + wid * 32, n0 = nc * 256;
  int row = lane & 15, hi = lane >> 4;

  bf16x8 qf[2][12];
  #pragma unroll
  for (int s = 0; s < 2; s++) {
    const bf16* qrow = Qb + ((size_t)(b * MM + m0 + s * 16 + row)) * AA + hi * 8;
    #pragma unroll
    for (int ks = 0; ks < 12; ks++) qf[s][ks] = *reinterpret_cast<const bf16x8*>(qrow + ks * 32);
  }

  int ldso[6], srco[6];
  #pragma unroll
  for (int i = 0; i < 6; i++) {
    int off = tid * 16 + i * 4096;
    int rw = off / KROW_B, c = off - rw * KROW_B;
    ldso[i] = off;
    srco[i] = rw * KROW_B + (c ^ ((rw & 7) << 4));
  }
  const char* kgbase = (const char*)(Kb + ((size_t)(b * NN + n0)) * AA);

  int sw = (row & 7) << 4;
  int rbase = row * KROW_B;
  int x0 = rbase + ((hi * 16) ^ sw);
  int x1 = rbase + (((hi * 16) + 64) ^ sw);

  float zacc[2][NH][4];
  #pragma unroll
  for (int s = 0; s < 2; s++)
    #pragma unroll
    for (int h = 0; h < NH; h++)
      #pragma unroll
      for (int j = 0; j < 4; j++) zacc[s][h][j] = 0.f;

  auto stage = [&](int t, int buf) {
    const char* src = kgbase + (size_t)t * STILE_B;
    #pragma unroll
    for (int i = 0; i < 6; i++) ld_lds16(src + srco[i], kbuf[buf] + ldso[i]);
  };
  auto compute = [&](int buf) {
    __builtin_amdgcn_s_setprio(1);
    #pragma unroll
    for (int sub = 0; sub < 2; sub++) {
      const char* kb = kbuf[buf] + sub * TILE_B;
      #pragma unroll
      for (int h = 0; h < NH; h++) {
        bf16x8 k0 = *reinterpret_cast<const bf16x8*>(kb + h * 128 + x0);
        bf16x8 k1 = *reinterpret_cast<const bf16x8*>(kb + h * 128 + x1);
        f32x4 a0 = {0.f, 0.f, 0.f, 0.f}, a1 = {0.f, 0.f, 0.f, 0.f};
        a0 = mfma16(qf[0][2 * h], k0, a0);
        a1 = mfma16(qf[1][2 * h], k0, a1);
        a0 = mfma16(qf[0][2 * h + 1], k1, a0);
        a1 = mfma16(qf[1][2 * h + 1], k1, a1);
        #pragma unroll
        for (int j = 0; j < 4; j++) {
          zacc[0][h][j] += __builtin_amdgcn_exp2f(a0[j]);
          zacc[1][h][j] += __builtin_amdgcn_exp2f(a1[j]);
        }
      }
    }
    __builtin_amdgcn_s_setprio(0);
  };

  stage(0, 0);
  asm volatile("s_waitcnt vmcnt(0)" ::: "memory");
  __builtin_amdgcn_s_barrier();
  __builtin_amdgcn_sched_barrier(0);
  stage(1, 1);
  compute(0);

  #pragma unroll 1
  for (int i = 1; i < 8; i++) {
    asm volatile("s_waitcnt vmcnt(0)" ::: "memory");
    __builtin_amdgcn_s_barrier();
    __builtin_amdgcn_sched_barrier(0);
    if (i < 7) stage(i + 1, (i + 1) & 1);
    compute(i & 1);
  }

  #pragma unroll
  for (int s = 0; s < 2; s++)
    #pragma unroll
    for (int h = 0; h < NH; h++)
      #pragma unroll
      for (int j = 0; j < 4; j++) {
        float v = zacc[s][h][j];
        v += __shfl_xor(v, 1); v += __shfl_xor(v, 2);
        v += __shfl_xor(v, 4); v += __shfl_xor(v, 8);
        zacc[s][h][j] = v;
      }
  if (row == 0) {
    #pragma unroll
    for (int s = 0; s < 2; s++)
      #pragma unroll
      for (int h = 0; h < NH; h++)
        #pragma unroll
        for (int j = 0; j < 4; j++)
          Zp[(((size_t)nc * 8 + b) * NH + h) * MM + m0 + s * 16 + hi * 4 + j] = zacc[s][h][j];
  }
}

// ---------------- pass 2: W2[b][m/4][sorted n][4] bf16; lrz folded into MFMA C-init ----------------
// grid = 512
__global__ __launch_bounds__(256, 2) void wpass_kernel(
    const bf16* __restrict__ Qb, const bf16* __restrict__ Kb,
    const float* __restrict__ Zp, bf16* __restrict__ W2)
{
  __shared__ char kbuf[2][STILE_B];    // 48 KB
  int id = blockIdx.x;
  int b = id & 7, r = id >> 3, mt = r & 7, nc = r >> 3;
  int tid = threadIdx.x, wid = tid >> 6, lane = tid & 63;
  int m0 = mt * 128 + wid * 32, n0 = nc * 256;
  int row = lane & 15, hi = lane >> 4;

  bf16x8 qf[2][12];
  #pragma unroll
  for (int s = 0; s < 2; s++) {
    const bf16* qrow = Qb + ((size_t)(b * MM + m0 + s * 16 + row)) * AA + hi * 8;
    #pragma unroll
    for (int ks = 0; ks < 12; ks++) qf[s][ks] = *reinterpret_cast<const bf16x8*>(qrow + ks * 32);
  }

  f32x4 lrz4[2][NH];
  #pragma unroll
  for (int s = 0; s < 2; s++)
    #pragma unroll
    for (int h = 0; h < NH; h++) {
      f32x4 z = {0.f, 0.f, 0.f, 0.f};
      #pragma unroll
      for (int p = 0; p < 8; p++)
        z += *reinterpret_cast<const f32x4*>(Zp + (((size_t)p * 8 + b) * NH + h) * MM + m0 + s * 16 + hi * 4);
      f32x4 l;
      #pragma unroll
      for (int j = 0; j < 4; j++) l[j] = -__log2f(6.0f * z[j]);
      lrz4[s][h] = l;
    }

  int ldso[6], srco[6];
  #pragma unroll
  for (int i = 0; i < 6; i++) {
    int off = tid * 16 + i * 4096;
    int rw = off / KROW_B, c = off - rw * KROW_B;
    ldso[i] = off;
    srco[i] = rw * KROW_B + (c ^ ((rw & 7) << 4));
  }
  const char* kgbase = (const char*)(Kb + ((size_t)(b * NN + n0)) * AA);

  int sw = (row & 7) << 4;
  int rbase = row * KROW_B;
  int x0 = rbase + ((hi * 16) ^ sw);
  int x1 = rbase + (((hi * 16) + 64) ^ sw);

  int m4a = (m0 >> 2) + hi;
  int m4b = ((m0 + 16) >> 2) + hi;

  auto stage = [&](int t, int buf) {
    const char* src = kgbase + (size_t)t * STILE_B;
    #pragma unroll
    for (int i = 0; i < 6; i++) ld_lds16(src + srco[i], kbuf[buf] + ldso[i]);
  };
  auto compute = [&](int buf, int st) {          // issues 4 x 8B stores
    #pragma unroll
    for (int sub = 0; sub < 2; sub++) {
      const char* kb = kbuf[buf] + sub * TILE_B;
      __builtin_amdgcn_s_setprio(1);
      float w0a = 0.f, w1a = 0.f, w2a = 0.f, w3a = 0.f;
      float w0b = 0.f, w1b = 0.f, w2b = 0.f, w3b = 0.f;
      #pragma unroll
      for (int h = 0; h < NH; h++) {
        bf16x8 k0 = *reinterpret_cast<const bf16x8*>(kb + h * 128 + x0);
        bf16x8 k1 = *reinterpret_cast<const bf16x8*>(kb + h * 128 + x1);
        f32x4 a0 = mfma16(qf[0][2 * h], k0, lrz4[0][h]);
        f32x4 a1 = mfma16(qf[1][2 * h], k0, lrz4[1][h]);
        a0 = mfma16(qf[0][2 * h + 1], k1, a0);
        a1 = mfma16(qf[1][2 * h + 1], k1, a1);
        w0a += __builtin_amdgcn_exp2f(a0[0]);
        w1a += __builtin_amdgcn_exp2f(a0[1]);
        w2a += __builtin_amdgcn_exp2f(a0[2]);
        w3a += __builtin_amdgcn_exp2f(a0[3]);
        w0b += __builtin_amdgcn_exp2f(a1[0]);
        w1b += __builtin_amdgcn_exp2f(a1[1]);
        w2b += __builtin_amdgcn_exp2f(a1[2]);
        w3b += __builtin_amdgcn_exp2f(a1[3]);
      }
      __builtin_amdgcn_s_setprio(0);
      int n = n0 + (st * 2 + sub) * 16 + row;
      ushort4 qa, qb2;
      qa.x = f2bfu(w0a); qa.y = f2bfu(w1a); qa.z = f2bfu(w2a); qa.w = f2bfu(w3a);
      qb2.x = f2bfu(w0b); qb2.y = f2bfu(w1b); qb2.z = f2bfu(w2b); qb2.w = f2bfu(w3b);
      *reinterpret_cast<ushort4*>((unsigned short*)W2 + (((size_t)(b * 256 + m4a)) * NN + n) * 4) = qa;
      *reinterpret_cast<ushort4*>((unsigned short*)W2 + (((size_t)(b * 256 + m4b)) * NN + n) * 4) = qb2;
    }
  };

  stage(0, 0);
  asm volatile("s_waitcnt vmcnt(0)" ::: "memory");
  __builtin_amdgcn_s_barrier();
  __builtin_amdgcn_sched_barrier(0);
  stage(1, 1);
  compute(0, 0);

  #pragma unroll 1
  for (int i = 1; i < 8; i++) {
    // queue: [S(i-2):<=4, L(i):6, S(i-1):4] -> vmcnt(4) retires through L(i)
    asm volatile("s_waitcnt vmcnt(4)" ::: "memory");
    __builtin_amdgcn_s_barrier();
    __builtin_amdgcn_sched_barrier(0);
    if (i < 7) stage(i + 1, (i + 1) & 1);
    compute(i & 1, i);
  }
}

// ---------------- pass 3: sorted-run gather + log. grid = 8b x 128 mt(8m) = 1024 ----------------
__global__ __launch_bounds__(512) void gather_kernel(
    const bf16* __restrict__ W2, const int* __restrict__ offs, float* __restrict__ out)
{
  __shared__ char wl[2 * NN * 8];       // 32 KB: 2 m4-groups x 2048 sorted-n x ushort4
  int id = blockIdx.x;
  int b = id & 7, mt = id >> 3;
  int g0 = mt * 2;
  int tid = threadIdx.x;

  const uint4* src = (const uint4*)((const unsigned short*)W2 + ((size_t)(b * 256 + g0)) * NN * 4);
  uint4* dst = (uint4*)wl;
  #pragma unroll
  for (int i = tid; i < 2 * NN * 8 / 16; i += 512) dst[i] = src[i];
  __syncthreads();

  int c = tid;
  int o0 = offs[b * (CC + 1) + c], o1 = offs[b * (CC + 1) + c + 1];
  #pragma unroll 1
  for (int g = 0; g < 2; g++) {
    const char* base = wl + g * (NN * 8);
    float s0 = 0.f, s1 = 0.f, s2 = 0.f, s3 = 0.f;
    #pragma unroll 1
    for (int i = o0; i < o1; i++) {
      ushort4 v = *reinterpret_cast<const ushort4*>(base + (size_t)i * 8);
      s0 += bf2f(v.x); s1 += bf2f(v.y); s2 += bf2f(v.z); s3 += bf2f(v.w);
    }
    int m = mt * 8 + g * 4;
    out[((size_t)(m + 0) * BQ + b) * CC + c] = __logf(fmaxf(s0, 1e-5f) + 3e-5f);
    out[((size_t)(m + 1) * BQ + b) * CC + c] = __logf(fmaxf(s1, 1e-5f) + 3e-5f);
    out[((size_t)(m + 2) * BQ + b) * CC + c] = __logf(fmaxf(s2, 1e-5f) + 3e-5f);
    out[((size_t)(m + 3) * BQ + b) * CC + c] = __logf(fmaxf(s3, 1e-5f) + 3e-5f);
  }
}

extern "C" void kernel_launch(void* const* d_in, const int* in_sizes, int n_in,
                              void* d_out, int out_size, void* d_ws, size_t ws_size,
                              hipStream_t stream) {
  const float* train = (const float*)d_in[0];
  const float* test  = (const float*)d_in[1];
  const int*   tgt   = (const int*)d_in[2];
  const float* Wq    = (const float*)d_in[3];
  const float* bq    = (const float*)d_in[4];
  const float* Wk    = (const float*)d_in[5];
  const float* bk    = (const float*)d_in[6];
  float* out = (float*)d_out;

  char* ws = (char*)d_ws;
  bf16*  WqT  = (bf16*)(ws);                       //    393,216 B
  bf16*  WkT  = (bf16*)(ws + 393216);              //    393,216 B
  bf16*  Qb   = (bf16*)(ws + 786432);              //  6,291,456 B
  bf16*  Kb   = (bf16*)(ws + 7077888);             // 12,582,912 B (class-sorted rows)
  float* Zp   = (float*)(ws + 19660800);           //  1,572,864 B
  bf16*  Wbuf = (bf16*)(ws + 21233664);            // 33,554,432 B (sorted n-axis)
  int*   offs = (int*)(ws + 54788096);             //     16,416 B
  int*   idxs = (int*)(ws + 54804512);             //     65,536 B

  prep_kernel<<<104, 512, 0, stream>>>(Wq, Wk, WqT, WkT, tgt, offs, idxs);
  proj_kernel<<<768, 256, 0, stream>>>(test, train, WqT, WkT, bq, bk, idxs, Qb, Kb);
  zpass_kernel<<<512, 256, 0, stream>>>(Qb, Kb, Zp);
  wpass_kernel<<<512, 256, 0, stream>>>(Qb, Kb, Zp, Wbuf);
  gather_kernel<<<1024, 512, 0, stream>>>(Wbuf, offs, out);
}